// Round 9
// baseline (811.349 us; speedup 1.0000x reference)
//
#include <hip/hip_runtime.h>
#include <hip/hip_bf16.h>

typedef unsigned short u16;
typedef unsigned char  u8;
typedef unsigned int   u32;
typedef unsigned long long u64;
typedef long long ll;

using short8 = __attribute__((ext_vector_type(8))) short;
using f32x4  = __attribute__((ext_vector_type(4))) float;
using u16x8  = __attribute__((ext_vector_type(8))) unsigned short;
using ll2    = __attribute__((ext_vector_type(2))) long long;

#define AS_GLOBAL __attribute__((address_space(1)))
#define AS_LDS    __attribute__((address_space(3)))

// ---- bf16 helpers (manual RNE) ----
__device__ __forceinline__ u16 f2b(float x){
  u32 u = __float_as_uint(x);
  u32 r = (u + 0x7FFFu + ((u >> 16) & 1u)) >> 16;
  return (u16)r;
}
__device__ __forceinline__ float b2f(u16 h){ return __uint_as_float(((u32)h) << 16); }

// ---- fp8 OCP e4m3 (RNE, saturate 448) ----
__device__ __forceinline__ u32 f2e4m3(float x){
  float ax = fabsf(x);
  u32 s = (__float_as_uint(x) & 0x80000000u) >> 24;
  ax = fminf(ax, 448.0f);
  if (ax < 0.015625f){
    u32 m = (u32)__float2int_rn(ax * 512.0f);
    return s | m;
  }
  u32 u = __float_as_uint(ax);
  u32 man = u & 0x7FFFFFu;
  u32 rnd = man + 0x7FFFFu + ((man >> 20) & 1u);
  u32 e = (u >> 23) + (rnd >> 23);
  u32 m = (rnd >> 23) ? 0u : ((rnd >> 20) & 7u);
  if (e > 135u) return s | 0x7Eu;
  return s | ((e - 120u) << 3) | m;
}

__device__ __forceinline__ void gload16(u16* l, const u16* g){
  __builtin_amdgcn_global_load_lds((const AS_GLOBAL u32*)g, (AS_LDS u32*)l, 16, 0, 0);
}

__device__ __forceinline__ u64 umin64(u64 a, u64 b){ return a < b ? a : b; }

__device__ __forceinline__ u64 shfl_xor_u64(u64 v, int m){
  u32 lo = __shfl_xor((u32)v, m, 64);
  u32 hi = __shfl_xor((u32)(v >> 32), m, 64);
  return ((u64)hi << 32) | lo;
}

// ---- prep kernels ----
__global__ void k_cvt(const float* __restrict__ w, u16* __restrict__ d, int n){
  int i = blockIdx.x * 256 + threadIdx.x;
  if (i < n) d[i] = f2b(w[i]);
}

// emb f32 [4096][512] -> emb8 fp8 [4096][512B], K permuted: row byte
// pb = kb*64 + g*16 + ks*8 + j  <->  k = kb*64 + ks*32 + g*8 + j ; scale 2^20
__global__ void k_cvt8(const float* __restrict__ src, u8* __restrict__ dst){
  int id = blockIdx.x * 256 + threadIdx.x;
  int row = id >> 7, db = id & 127;
  int b0 = db * 4;
  int kb = b0 >> 6, r6 = b0 & 63;
  int g = r6 >> 4, ks = (r6 >> 3) & 1, j0 = r6 & 7;
  int k = kb * 64 + ks * 32 + g * 8 + j0;
  const float* p = src + (size_t)row * 512 + k;
  u32 w = f2e4m3(p[0] * 1048576.0f)
        | (f2e4m3(p[1] * 1048576.0f) << 8)
        | (f2e4m3(p[2] * 1048576.0f) << 16)
        | (f2e4m3(p[3] * 1048576.0f) << 24);
  *(u32*)(dst + (size_t)row * 512 + b0) = w;
}

// cnorm scaled by 2^26 (matches fp8 score scale 2^20 * 2^6)
__global__ void k_cnorm(const float* __restrict__ emb, float* __restrict__ cn26){
  int v = blockIdx.x, lane = threadIdx.x;
  const float* r = emb + (size_t)v * 512;
  float s = 0.f;
  #pragma unroll
  for (int i = 0; i < 8; ++i){ float x = r[lane + i * 64]; s += x * x; }
  #pragma unroll
  for (int off = 32; off; off >>= 1) s += __shfl_down(s, off, 64);
  if (lane == 0) cn26[v] = s * 67108864.0f;
}

// ---- transpose+convert: x f32 [256 b][512 r][256 c] -> xb bf16 [b][c][r] ----
__global__ void k_tcvt(const float* __restrict__ src, u16* __restrict__ d){
  __shared__ float t[64][65];
  const int bid = blockIdx.x;
  const int b  = bid >> 5;
  const int rb = (bid >> 2) & 7;
  const int cb = bid & 3;
  const float* s = src + ((size_t)b * 512 + (size_t)rb * 64) * 256 + cb * 64;
  const int tid = threadIdx.x;
  #pragma unroll
  for (int j = 0; j < 4; ++j){
    int fl = j * 256 + tid;
    int r = fl >> 4, c4 = (fl & 15) * 4;
    float4 v = *(const float4*)(s + (size_t)r * 256 + c4);
    t[r][c4 + 0] = v.x; t[r][c4 + 1] = v.y; t[r][c4 + 2] = v.z; t[r][c4 + 3] = v.w;
  }
  __syncthreads();
  u16* o = d + ((size_t)b * 256 + (size_t)cb * 64) * 512 + rb * 64;
  #pragma unroll
  for (int j = 0; j < 2; ++j){
    int fl = j * 256 + tid;
    int c = fl >> 3, r8 = (fl & 7) * 8;
    u16x8 hv;
    #pragma unroll
    for (int i = 0; i < 8; ++i) hv[i] = f2b(t[r8 + i][c]);
    *(u16x8*)(o + (size_t)c * 512 + r8) = hv;
  }
}

// ---- z_q gather ----
__global__ void k_zq(const u64* __restrict__ keys, const float* __restrict__ emb, float* __restrict__ zq){
  int sidx = blockIdx.x * 64 + threadIdx.x;
  int b = sidx >> 8, s = sidx & 255;
  int v = (int)(u32)keys[sidx];
  const float4* er = (const float4*)(emb + (size_t)v * 512);
  float* o = zq + (size_t)b * 512 * 256 + s;
  #pragma unroll 4
  for (int e4 = 0; e4 < 128; ++e4){
    float4 vv = er[e4];
    o[(size_t)(e4 * 4 + 0) * 256] = vv.x;
    o[(size_t)(e4 * 4 + 1) * 256] = vv.y;
    o[(size_t)(e4 * 4 + 2) * 256] = vv.z;
    o[(size_t)(e4 * 4 + 3) * 256] = vv.w;
  }
}

// ---- small GEMM (proven 128x128 2-phase): GEMM1 & GEMM3 ----
// MODE 0 additionally writes z8 = fp8(z*64) permK transposed from registers.
template<int MODE>
__global__ __launch_bounds__(256, 4) void k_gemm(
    const u16* __restrict__ Ah,
    const u16* __restrict__ Bh,
    const u64* __restrict__ gkeys,
    const float* __restrict__ bias,
    float* __restrict__ Cout,
    u8* __restrict__ Z8,
    int M, int mtbits)
{
  constexpr int K = 512;
  __shared__ __align__(16) u16 sA[128 * 64];
  __shared__ __align__(16) u16 sB[128 * 64];

  const int tid  = threadIdx.x;
  const int lane = tid & 63;
  const int wid  = tid >> 6;
  const int wm = wid >> 1, wn = wid & 1;

  const int nwg = gridDim.x;
  const int chunk = nwg >> 3;
  const int pb = blockIdx.x;
  const int bid = (pb & 7) * chunk + (pb >> 3);

  const int mt = bid & ((1 << mtbits) - 1);
  const int nt = (bid >> mtbits) & 1;
  const int b  = bid >> (mtbits + 1);
  const int m0 = mt * 128;
  const int n0 = nt * 128;
  const int bbase = b * 256;

  const u16* ga[4];
  const u16* gb[4];
  int ldso[4];
  #pragma unroll
  for (int i = 0; i < 4; ++i){
    int e = i * 256 + tid;
    int r = e >> 3;
    int sl = (e & 7) ^ (r & 7);
    ldso[i] = e * 8;
    ga[i] = Ah + (size_t)(m0 + r) * K + sl * 8;
    size_t brow;
    if (MODE == 2) brow = (size_t)(u32)gkeys[bbase + n0 + r];
    else           brow = (size_t)(bbase + n0 + r);
    gb[i] = Bh + brow * K + sl * 8;
  }

  const f32x4 zero4 = {0.f, 0.f, 0.f, 0.f};
  f32x4 acc[4][4];
  #pragma unroll
  for (int i = 0; i < 4; ++i)
    #pragma unroll
    for (int j = 0; j < 4; ++j) acc[i][j] = zero4;

  int aoff[2][4], boff[2][4];
  #pragma unroll
  for (int ks = 0; ks < 2; ++ks)
    #pragma unroll
    for (int f = 0; f < 4; ++f){
      int rA = wm * 64 + f * 16 + (lane & 15);
      aoff[ks][f] = rA * 64 + (((ks * 4 + (lane >> 4)) ^ (rA & 7)) * 8);
      int rB = wn * 64 + f * 16 + (lane & 15);
      boff[ks][f] = rB * 64 + (((ks * 4 + (lane >> 4)) ^ (rB & 7)) * 8);
    }

  for (int kt = 0; kt < 8; ++kt){
    const int k0 = kt * 64;
    #pragma unroll
    for (int i = 0; i < 4; ++i){
      gload16(&sA[ldso[i]], ga[i] + k0);
      gload16(&sB[ldso[i]], gb[i] + k0);
    }
    __syncthreads();
    #pragma unroll
    for (int ks = 0; ks < 2; ++ks){
      short8 ah[4], bh[4];
      #pragma unroll
      for (int f = 0; f < 4; ++f){
        ah[f] = *(const short8*)&sA[aoff[ks][f]];
        bh[f] = *(const short8*)&sB[boff[ks][f]];
      }
      #pragma unroll
      for (int fm = 0; fm < 4; ++fm)
        #pragma unroll
        for (int fn = 0; fn < 4; ++fn)
          acc[fm][fn] = __builtin_amdgcn_mfma_f32_16x16x32_bf16(ah[fm], bh[fn], acc[fm][fn], 0, 0, 0);
    }
    __syncthreads();
  }

  const int row0 = m0 + wm * 64;
  const int col  = n0 + wn * 64 + (lane & 15);
  float* Cb = Cout + (size_t)b * M * 256;
  #pragma unroll
  for (int fm = 0; fm < 4; ++fm){
    #pragma unroll
    for (int j = 0; j < 4; ++j){
      int row = row0 + fm * 16 + (lane >> 4) * 4 + j;
      float bi = bias[row];
      #pragma unroll
      for (int fn = 0; fn < 4; ++fn)
        Cb[(size_t)row * 256 + col + fn * 16] = acc[fm][fn][j] + bi;
    }
  }

  if (MODE == 0){
    // z8[(b*256+tok)][pb(k)] = fp8(z_k*64), pb = kb*64 + g*16 + ks*8 + j
    #pragma unroll
    for (int fm = 0; fm < 4; ++fm){
      int rb4 = row0 + fm * 16 + (lane >> 4) * 4;
      int pb0 = (rb4 >> 6) * 64 + (((rb4 >> 3) & 3) * 16) + (((rb4 >> 5) & 1) * 8) + (rb4 & 7);
      float bi0 = bias[rb4], bi1 = bias[rb4+1], bi2 = bias[rb4+2], bi3 = bias[rb4+3];
      #pragma unroll
      for (int fn = 0; fn < 4; ++fn){
        u32 w = f2e4m3((acc[fm][fn][0] + bi0) * 64.0f)
              | (f2e4m3((acc[fm][fn][1] + bi1) * 64.0f) << 8)
              | (f2e4m3((acc[fm][fn][2] + bi2) * 64.0f) << 16)
              | (f2e4m3((acc[fm][fn][3] + bi3) * 64.0f) << 24);
        *(u32*)(Z8 + (size_t)(bbase + col + fn * 16) * 512 + pb0) = w;
      }
    }
  }
}

// ---- GEMM2: fp8, B LDS-resident, A direct-from-L2 into registers ----
// One block per batch (256 blocks, 512 thr, 8 waves 2x4, 1/CU).
// B = z8 panel: 128KB LDS-resident, slot-XOR s^(t&31) (read conflict-free:
// bank-group = (s%8)^(t&7) covers all 8). cn26 in LDS (broadcast reads).
// A = emb8 (2MB, L2-resident): each wave loads its 8 fragments/tile DIRECTLY
// from global into registers, named double-buffer afA/afB (rule #20), issued
// one tile ahead -> L2 latency (~200cy) hidden under MFMA (~2500cy/tile).
// NO LDS staging for A, NO barriers in the main loop: waves drift freely so
// one wave's MFMA overlaps another's loads (escapes the lockstep seriality
// that pinned rounds 4/7/8 at 322us). Compiler inserts vmcnt/lgkm waits.
// Accumulation order per acc element identical to round 8 -> same tokens.
__global__ __launch_bounds__(512, 1) void k_gemm2(
    const u8* __restrict__ A8,      // emb8 [4096][512B permK]
    const u8* __restrict__ B8,      // z8 [65536][512B permK]
    const float* __restrict__ cn26,
    u64* __restrict__ okeys)
{
  __shared__ __align__(16) u8 lds[151552];  // B 0..131071 | cn 131072..147455 | kbuf 147456..

  const int tid  = threadIdx.x;
  const int lane = tid & 63;
  const int wid  = tid >> 6;
  const int wm   = wid >> 2;
  const int wn   = wid & 3;
  const int b    = blockIdx.x;
  const int bbase = b * 256;
  const int g4   = lane >> 4;

  // ---- B init: 128KB resident (pre-unswizzled source, linear gload_lds dest) ----
  #pragma unroll
  for (int i = 0; i < 16; ++i){
    int e = i * 512 + tid;          // 16B-slot id 0..8191
    int t = e >> 5, s = e & 31;
    gload16((u16*)&lds[e * 16],
            (const u16*)(B8 + (size_t)(bbase + t) * 512 + ((s ^ (t & 31)) * 16)));
  }
  // cn26 -> LDS
  {
    const float4* c4 = (const float4*)cn26;
    float4 v0 = c4[tid], v1 = c4[tid + 512];
    *(float4*)&lds[131072 + tid * 16] = v0;
    *(float4*)&lds[131072 + (tid + 512) * 16] = v1;
  }
  asm volatile("s_waitcnt vmcnt(0)" ::: "memory");
  __syncthreads();

  // per-lane A voffset (bytes): row = wm*128 + fm*16 + (lane&15), slot g4
  const u32 abase = (u32)((wm * 128 + (lane & 15)) * 512 + g4 * 16);

#define LOAD_A(dst, tau_) { const u32 o_ = ((((tau_) & 127) >> 3) * 131072u) + (((tau_) & 7) * 64u); \
    _Pragma("unroll") for (int fm = 0; fm < 8; ++fm) \
      dst[fm] = *(const ll2*)(A8 + abase + fm * 8192u + o_); }
#define READ_B(kt_) { _Pragma("unroll") for (int fn = 0; fn < 4; ++fn){ \
    int t_ = wn * 64 + fn * 16 + (lane & 15); \
    bv[fn] = *(const ll2*)&lds[t_ * 512 + ((((kt_) * 4 + g4) ^ (t_ & 31)) * 16)]; } }
#define MM(af) { __builtin_amdgcn_s_setprio(1); \
  _Pragma("unroll") for (int fm = 0; fm < 8; ++fm) \
    _Pragma("unroll") for (int fn = 0; fn < 4; ++fn){ \
      acc[fm][fn] = __builtin_amdgcn_mfma_f32_16x16x32_fp8_fp8(af[fm][0], bv[fn][0], acc[fm][fn], 0, 0, 0); \
      acc[fm][fn] = __builtin_amdgcn_mfma_f32_16x16x32_fp8_fp8(af[fm][1], bv[fn][1], acc[fm][fn], 0, 0, 0); } \
  __builtin_amdgcn_s_setprio(0); }

  const f32x4 zero4 = {0.f, 0.f, 0.f, 0.f};
  f32x4 acc[8][4];
  #pragma unroll
  for (int i = 0; i < 8; ++i)
    #pragma unroll
    for (int j = 0; j < 4; ++j) acc[i][j] = zero4;

  u64 best[4];
  #pragma unroll
  for (int i = 0; i < 4; ++i) best[i] = ~0ull;

  ll2 afA[8], afB[8], bv[4];
  LOAD_A(afA, 0)

  for (int mt = 0; mt < 16; ++mt){
    #pragma unroll
    for (int kp = 0; kp < 4; ++kp){
      const int tau = mt * 8 + kp * 2;
      LOAD_A(afB, tau + 1)
      READ_B(kp * 2)
      MM(afA)
      LOAD_A(afA, tau + 2)
      READ_B(kp * 2 + 1)
      MM(afB)
    }

    // per-mt epilogue: scores from LDS-resident cn26 (broadcast), fold argmin
    {
      const int cnb = 131072 + (mt * 256 + wm * 128 + g4 * 4) * 4;
      #pragma unroll
      for (int fn = 0; fn < 4; ++fn){
        #pragma unroll
        for (int fm = 0; fm < 8; ++fm){
          float4 cnr = *(const float4*)&lds[cnb + fm * 64];
          #pragma unroll
          for (int jj = 0; jj < 4; ++jj){
            int v = mt * 256 + wm * 128 + fm * 16 + g4 * 4 + jj;
            float sc = ((const float*)&cnr)[jj] - 2.0f * acc[fm][fn][jj];
            u32 o = __float_as_uint(sc);
            o = (o & 0x80000000u) ? ~o : (o | 0x80000000u);
            best[fn] = umin64(best[fn], ((u64)o << 32) | (u32)v);
          }
        }
      }
      #pragma unroll
      for (int i = 0; i < 8; ++i)
        #pragma unroll
        for (int jj = 0; jj < 4; ++jj) acc[i][jj] = zero4;
    }
  }

  // block reduce + single store
  #pragma unroll
  for (int fn = 0; fn < 4; ++fn){
    best[fn] = umin64(best[fn], shfl_xor_u64(best[fn], 16));
    best[fn] = umin64(best[fn], shfl_xor_u64(best[fn], 32));
  }
  __syncthreads();
  u64* kbuf = (u64*)&lds[147456];
  if (lane < 16){
    #pragma unroll
    for (int fn = 0; fn < 4; ++fn)
      kbuf[wm * 256 + wn * 64 + fn * 16 + lane] = best[fn];
  }
  __syncthreads();
  if (tid < 256)
    okeys[bbase + tid] = umin64(kbuf[tid], kbuf[256 + tid]);

#undef LOAD_A
#undef READ_B
#undef MM
}

extern "C" void kernel_launch(void* const* d_in, const int* in_sizes, int n_in,
                              void* d_out, int out_size, void* d_ws, size_t ws_size,
                              hipStream_t stream){
  const float* x      = (const float*)d_in[0];
  const float* pre_w  = (const float*)d_in[1];
  const float* pre_b  = (const float*)d_in[2];
  const float* emb    = (const float*)d_in[3];
  const float* post_w = (const float*)d_in[4];
  const float* post_b = (const float*)d_in[5];

  float* z_out   = (float*)d_out;              // [256][512][256]
  float* zq_out  = z_out + 33554432;           // [256][512][256]
  float* rec_out = z_out + 67108864;           // [256][512][256]

  char* w = (char*)d_ws;
  u16* prew_b  = (u16*)(w);                    // 512KB
  u16* postw_b = (u16*)(w + 524288);           // 512KB
  u16* emb_b   = (u16*)(w + 1048576);          // 4MB (bf16, GEMM3)
  u8*  emb8    = (u8*)(w + 5242880);           // 2MB (fp8 permK)
  float* cn26  = (float*)(w + 7340032);        // 16KB
  u64* keys    = (u64*)(w + 7356416);          // 512KB
  u16* xb      = (u16*)(w + 7880704);          // 64MB [65536][512] bf16 (x^T)
  u8*  z8      = (u8*)(w + 74989568);          // 32MB [65536][512B] fp8 permK (z^T)

  k_cvt  <<<1024, 256, 0, stream>>>(pre_w, prew_b, 262144);
  k_cvt  <<<1024, 256, 0, stream>>>(post_w, postw_b, 262144);
  k_cvt  <<<8192, 256, 0, stream>>>(emb, emb_b, 2097152);
  k_cvt8 <<<2048, 256, 0, stream>>>(emb, emb8);
  k_cnorm<<<4096, 64, 0, stream>>>(emb, cn26);

  // x [b][c][s] -> xb [b][s][c]
  k_tcvt<<<8192, 256, 0, stream>>>(x, xb);

  // GEMM1: z = pre_w * x + pre_b ; fused z8 (fp8 permK transposed) write
  k_gemm<0><<<256 * 2 * 4, 256, 0, stream>>>(prew_b, xb,
      nullptr, pre_b, z_out, z8, 512, 2);

  // GEMM2: fp8 scores + fused argmin -> keys (A from L2, barrier-free loop)
  k_gemm2<<<256, 512, 0, stream>>>(emb8, z8, cn26, keys);

  // z_q gather (exact f32)
  k_zq<<<1024, 64, 0, stream>>>(keys, emb, zq_out);

  // GEMM3: rec = post_w * z_q + post_b (B = emb_b rows gathered via tokens)
  k_gemm<2><<<256 * 2 * 4, 256, 0, stream>>>(postw_b, emb_b,
      keys, post_b, rec_out, nullptr, 512, 2);
}

// Round 10
// 780.222 us; speedup vs baseline: 1.0399x; 1.0399x over previous
//
#include <hip/hip_runtime.h>
#include <hip/hip_bf16.h>

typedef unsigned short u16;
typedef unsigned char  u8;
typedef unsigned int   u32;
typedef unsigned long long u64;
typedef long long ll;

using short8 = __attribute__((ext_vector_type(8))) short;
using f32x4  = __attribute__((ext_vector_type(4))) float;
using u16x8  = __attribute__((ext_vector_type(8))) unsigned short;
using ll2    = __attribute__((ext_vector_type(2))) long long;

#define AS_GLOBAL __attribute__((address_space(1)))
#define AS_LDS    __attribute__((address_space(3)))

// ---- bf16 helpers (manual RNE) ----
__device__ __forceinline__ u16 f2b(float x){
  u32 u = __float_as_uint(x);
  u32 r = (u + 0x7FFFu + ((u >> 16) & 1u)) >> 16;
  return (u16)r;
}
__device__ __forceinline__ float b2f(u16 h){ return __uint_as_float(((u32)h) << 16); }

// ---- fp8 OCP e4m3 (RNE, saturate 448) ----
__device__ __forceinline__ u32 f2e4m3(float x){
  float ax = fabsf(x);
  u32 s = (__float_as_uint(x) & 0x80000000u) >> 24;
  ax = fminf(ax, 448.0f);
  if (ax < 0.015625f){
    u32 m = (u32)__float2int_rn(ax * 512.0f);
    return s | m;
  }
  u32 u = __float_as_uint(ax);
  u32 man = u & 0x7FFFFFu;
  u32 rnd = man + 0x7FFFFu + ((man >> 20) & 1u);
  u32 e = (u >> 23) + (rnd >> 23);
  u32 m = (rnd >> 23) ? 0u : ((rnd >> 20) & 7u);
  if (e > 135u) return s | 0x7Eu;
  return s | ((e - 120u) << 3) | m;
}

__device__ __forceinline__ void gload16(u16* l, const u16* g){
  __builtin_amdgcn_global_load_lds((const AS_GLOBAL u32*)g, (AS_LDS u32*)l, 16, 0, 0);
}

__device__ __forceinline__ u64 umin64(u64 a, u64 b){ return a < b ? a : b; }

__device__ __forceinline__ u64 shfl_xor_u64(u64 v, int m){
  u32 lo = __shfl_xor((u32)v, m, 64);
  u32 hi = __shfl_xor((u32)(v >> 32), m, 64);
  return ((u64)hi << 32) | lo;
}

// ---- prep kernels ----
__global__ void k_cvt(const float* __restrict__ w, u16* __restrict__ d, int n){
  int i = blockIdx.x * 256 + threadIdx.x;
  if (i < n) d[i] = f2b(w[i]);
}

// emb f32 [4096][512] -> emb8 fp8 [4096][512B], K permuted: row byte
// pb = kb*64 + g*16 + ks*8 + j  <->  k = kb*64 + ks*32 + g*8 + j ; scale 2^20
__global__ void k_cvt8(const float* __restrict__ src, u8* __restrict__ dst){
  int id = blockIdx.x * 256 + threadIdx.x;
  int row = id >> 7, db = id & 127;
  int b0 = db * 4;
  int kb = b0 >> 6, r6 = b0 & 63;
  int g = r6 >> 4, ks = (r6 >> 3) & 1, j0 = r6 & 7;
  int k = kb * 64 + ks * 32 + g * 8 + j0;
  const float* p = src + (size_t)row * 512 + k;
  u32 w = f2e4m3(p[0] * 1048576.0f)
        | (f2e4m3(p[1] * 1048576.0f) << 8)
        | (f2e4m3(p[2] * 1048576.0f) << 16)
        | (f2e4m3(p[3] * 1048576.0f) << 24);
  *(u32*)(dst + (size_t)row * 512 + b0) = w;
}

// cnorm scaled by 2^26 (matches fp8 score scale 2^20 * 2^6)
__global__ void k_cnorm(const float* __restrict__ emb, float* __restrict__ cn26){
  int v = blockIdx.x, lane = threadIdx.x;
  const float* r = emb + (size_t)v * 512;
  float s = 0.f;
  #pragma unroll
  for (int i = 0; i < 8; ++i){ float x = r[lane + i * 64]; s += x * x; }
  #pragma unroll
  for (int off = 32; off; off >>= 1) s += __shfl_down(s, off, 64);
  if (lane == 0) cn26[v] = s * 67108864.0f;
}

// ---- transpose+convert: x f32 [256 b][512 r][256 c] -> xb bf16 [b][c][r] ----
__global__ void k_tcvt(const float* __restrict__ src, u16* __restrict__ d){
  __shared__ float t[64][65];
  const int bid = blockIdx.x;
  const int b  = bid >> 5;
  const int rb = (bid >> 2) & 7;
  const int cb = bid & 3;
  const float* s = src + ((size_t)b * 512 + (size_t)rb * 64) * 256 + cb * 64;
  const int tid = threadIdx.x;
  #pragma unroll
  for (int j = 0; j < 4; ++j){
    int fl = j * 256 + tid;
    int r = fl >> 4, c4 = (fl & 15) * 4;
    float4 v = *(const float4*)(s + (size_t)r * 256 + c4);
    t[r][c4 + 0] = v.x; t[r][c4 + 1] = v.y; t[r][c4 + 2] = v.z; t[r][c4 + 3] = v.w;
  }
  __syncthreads();
  u16* o = d + ((size_t)b * 256 + (size_t)cb * 64) * 512 + rb * 64;
  #pragma unroll
  for (int j = 0; j < 2; ++j){
    int fl = j * 256 + tid;
    int c = fl >> 3, r8 = (fl & 7) * 8;
    u16x8 hv;
    #pragma unroll
    for (int i = 0; i < 8; ++i) hv[i] = f2b(t[r8 + i][c]);
    *(u16x8*)(o + (size_t)c * 512 + r8) = hv;
  }
}

// ---- z_q gather ----
__global__ void k_zq(const u64* __restrict__ keys, const float* __restrict__ emb, float* __restrict__ zq){
  int sidx = blockIdx.x * 64 + threadIdx.x;
  int b = sidx >> 8, s = sidx & 255;
  int v = (int)(u32)keys[sidx];
  const float4* er = (const float4*)(emb + (size_t)v * 512);
  float* o = zq + (size_t)b * 512 * 256 + s;
  #pragma unroll 4
  for (int e4 = 0; e4 < 128; ++e4){
    float4 vv = er[e4];
    o[(size_t)(e4 * 4 + 0) * 256] = vv.x;
    o[(size_t)(e4 * 4 + 1) * 256] = vv.y;
    o[(size_t)(e4 * 4 + 2) * 256] = vv.z;
    o[(size_t)(e4 * 4 + 3) * 256] = vv.w;
  }
}

// ---- small GEMM (proven 128x128 2-phase): GEMM1 & GEMM3 ----
// MODE 0 additionally writes z8 = fp8(z*64) permK transposed from registers.
template<int MODE>
__global__ __launch_bounds__(256, 4) void k_gemm(
    const u16* __restrict__ Ah,
    const u16* __restrict__ Bh,
    const u64* __restrict__ gkeys,
    const float* __restrict__ bias,
    float* __restrict__ Cout,
    u8* __restrict__ Z8,
    int M, int mtbits)
{
  constexpr int K = 512;
  __shared__ __align__(16) u16 sA[128 * 64];
  __shared__ __align__(16) u16 sB[128 * 64];

  const int tid  = threadIdx.x;
  const int lane = tid & 63;
  const int wid  = tid >> 6;
  const int wm = wid >> 1, wn = wid & 1;

  const int nwg = gridDim.x;
  const int chunk = nwg >> 3;
  const int pb = blockIdx.x;
  const int bid = (pb & 7) * chunk + (pb >> 3);

  const int mt = bid & ((1 << mtbits) - 1);
  const int nt = (bid >> mtbits) & 1;
  const int b  = bid >> (mtbits + 1);
  const int m0 = mt * 128;
  const int n0 = nt * 128;
  const int bbase = b * 256;

  const u16* ga[4];
  const u16* gb[4];
  int ldso[4];
  #pragma unroll
  for (int i = 0; i < 4; ++i){
    int e = i * 256 + tid;
    int r = e >> 3;
    int sl = (e & 7) ^ (r & 7);
    ldso[i] = e * 8;
    ga[i] = Ah + (size_t)(m0 + r) * K + sl * 8;
    size_t brow;
    if (MODE == 2) brow = (size_t)(u32)gkeys[bbase + n0 + r];
    else           brow = (size_t)(bbase + n0 + r);
    gb[i] = Bh + brow * K + sl * 8;
  }

  const f32x4 zero4 = {0.f, 0.f, 0.f, 0.f};
  f32x4 acc[4][4];
  #pragma unroll
  for (int i = 0; i < 4; ++i)
    #pragma unroll
    for (int j = 0; j < 4; ++j) acc[i][j] = zero4;

  int aoff[2][4], boff[2][4];
  #pragma unroll
  for (int ks = 0; ks < 2; ++ks)
    #pragma unroll
    for (int f = 0; f < 4; ++f){
      int rA = wm * 64 + f * 16 + (lane & 15);
      aoff[ks][f] = rA * 64 + (((ks * 4 + (lane >> 4)) ^ (rA & 7)) * 8);
      int rB = wn * 64 + f * 16 + (lane & 15);
      boff[ks][f] = rB * 64 + (((ks * 4 + (lane >> 4)) ^ (rB & 7)) * 8);
    }

  for (int kt = 0; kt < 8; ++kt){
    const int k0 = kt * 64;
    #pragma unroll
    for (int i = 0; i < 4; ++i){
      gload16(&sA[ldso[i]], ga[i] + k0);
      gload16(&sB[ldso[i]], gb[i] + k0);
    }
    __syncthreads();
    #pragma unroll
    for (int ks = 0; ks < 2; ++ks){
      short8 ah[4], bh[4];
      #pragma unroll
      for (int f = 0; f < 4; ++f){
        ah[f] = *(const short8*)&sA[aoff[ks][f]];
        bh[f] = *(const short8*)&sB[boff[ks][f]];
      }
      #pragma unroll
      for (int fm = 0; fm < 4; ++fm)
        #pragma unroll
        for (int fn = 0; fn < 4; ++fn)
          acc[fm][fn] = __builtin_amdgcn_mfma_f32_16x16x32_bf16(ah[fm], bh[fn], acc[fm][fn], 0, 0, 0);
    }
    __syncthreads();
  }

  const int row0 = m0 + wm * 64;
  const int col  = n0 + wn * 64 + (lane & 15);
  float* Cb = Cout + (size_t)b * M * 256;
  #pragma unroll
  for (int fm = 0; fm < 4; ++fm){
    #pragma unroll
    for (int j = 0; j < 4; ++j){
      int row = row0 + fm * 16 + (lane >> 4) * 4 + j;
      float bi = bias[row];
      #pragma unroll
      for (int fn = 0; fn < 4; ++fn)
        Cb[(size_t)row * 256 + col + fn * 16] = acc[fm][fn][j] + bi;
    }
  }

  if (MODE == 0){
    // z8[(b*256+tok)][pb(k)] = fp8(z_k*64), pb = kb*64 + g*16 + ks*8 + j
    #pragma unroll
    for (int fm = 0; fm < 4; ++fm){
      int rb4 = row0 + fm * 16 + (lane >> 4) * 4;
      int pb0 = (rb4 >> 6) * 64 + (((rb4 >> 3) & 3) * 16) + (((rb4 >> 5) & 1) * 8) + (rb4 & 7);
      float bi0 = bias[rb4], bi1 = bias[rb4+1], bi2 = bias[rb4+2], bi3 = bias[rb4+3];
      #pragma unroll
      for (int fn = 0; fn < 4; ++fn){
        u32 w = f2e4m3((acc[fm][fn][0] + bi0) * 64.0f)
              | (f2e4m3((acc[fm][fn][1] + bi1) * 64.0f) << 8)
              | (f2e4m3((acc[fm][fn][2] + bi2) * 64.0f) << 16)
              | (f2e4m3((acc[fm][fn][3] + bi3) * 64.0f) << 24);
        *(u32*)(Z8 + (size_t)(bbase + col + fn * 16) * 512 + pb0) = w;
      }
    }
  }
}

// ---- GEMM2: fp8, B LDS-resident, A from L2 into regs, barrier-free loop ----
// 256 blocks (1/batch, 1/CU) x 256 thr (4 waves, 1/SIMD). Full 256-VGPR
// budget (r6-proven: 256-thr blocks allocate 256 VGPRs; 512-thr cap at 128
// caused r5/r9 spills). Per wave: tokens wn*64..+63, ALL A rows (mt=0..31,
// BM=128/tile). Registers: acc[8][4]=128, afA/afB (A frags, dbuf)=64,
// bvA/bvB (B frags, dbuf)=32, ~244 total.
// B = z8 panel 128KB LDS, slot-XOR s^(t&31) (r9-verified: 0 conflicts).
// A = emb8 (2MB, L2-resident): 8 dwordx4/wave/tile direct to regs, 1 tile
// ahead. NO barriers in loop -> waves drift, loads overlap MFMA.
// Per-wave argmin covers full vocab for its tokens -> direct store, no
// cross-wave reduce. Accumulation order identical to r8/r9 -> same tokens.
__global__ __launch_bounds__(256, 1) void k_gemm2(
    const u8* __restrict__ A8,      // emb8 [4096][512B permK]
    const u8* __restrict__ B8,      // z8 [65536][512B permK]
    const float* __restrict__ cn26,
    u64* __restrict__ okeys)
{
  __shared__ __align__(16) u8 lds[147456];  // B 0..131071 | cn 131072..147455

  const int tid  = threadIdx.x;
  const int lane = tid & 63;
  const int wn   = tid >> 6;
  const int b    = blockIdx.x;
  const int bbase = b * 256;
  const int g4   = lane >> 4;

  // ---- B init: 128KB resident (pre-unswizzled source, linear gload_lds dest) ----
  #pragma unroll
  for (int i = 0; i < 32; ++i){
    int e = i * 256 + tid;          // 16B-slot id 0..8191
    int t = e >> 5, s = e & 31;
    gload16((u16*)&lds[e * 16],
            (const u16*)(B8 + (size_t)(bbase + t) * 512 + ((s ^ (t & 31)) * 16)));
  }
  // cn26 -> LDS
  {
    const float4* c4 = (const float4*)cn26;
    #pragma unroll
    for (int i = 0; i < 4; ++i){
      float4 v = c4[tid + i * 256];
      *(float4*)&lds[131072 + (tid + i * 256) * 16] = v;
    }
  }
  asm volatile("s_waitcnt vmcnt(0)" ::: "memory");
  __syncthreads();

  // per-lane A byte offset within tile: row = fm*16 + (lane&15), slot g4
  const u32 abase = (u32)((lane & 15) * 512 + g4 * 16);

#define LOAD_A(dst, tau_) { const u32 o_ = ((((tau_) & 255) >> 3) * 65536u) + (((tau_) & 7) * 64u); \
    _Pragma("unroll") for (int fm = 0; fm < 8; ++fm) \
      dst[fm] = *(const ll2*)(A8 + abase + fm * 8192u + o_); }
#define READ_B(dst, kt_) { _Pragma("unroll") for (int fn = 0; fn < 4; ++fn){ \
    int t_ = wn * 64 + fn * 16 + (lane & 15); \
    dst[fn] = *(const ll2*)&lds[t_ * 512 + ((((kt_) * 4 + g4) ^ (t_ & 31)) * 16)]; } }
#define MM(af, bv) { __builtin_amdgcn_s_setprio(1); \
  _Pragma("unroll") for (int fm = 0; fm < 8; ++fm) \
    _Pragma("unroll") for (int fn = 0; fn < 4; ++fn){ \
      acc[fm][fn] = __builtin_amdgcn_mfma_f32_16x16x32_fp8_fp8(af[fm][0], bv[fn][0], acc[fm][fn], 0, 0, 0); \
      acc[fm][fn] = __builtin_amdgcn_mfma_f32_16x16x32_fp8_fp8(af[fm][1], bv[fn][1], acc[fm][fn], 0, 0, 0); } \
  __builtin_amdgcn_s_setprio(0); }

  const f32x4 zero4 = {0.f, 0.f, 0.f, 0.f};
  f32x4 acc[8][4];
  #pragma unroll
  for (int i = 0; i < 8; ++i)
    #pragma unroll
    for (int j = 0; j < 4; ++j) acc[i][j] = zero4;

  u64 best[4];
  #pragma unroll
  for (int i = 0; i < 4; ++i) best[i] = ~0ull;

  ll2 afA[8], afB[8], bvA[4], bvB[4];
  LOAD_A(afA, 0)
  READ_B(bvA, 0)

  for (int mt = 0; mt < 32; ++mt){
    #pragma unroll
    for (int kp = 0; kp < 4; ++kp){
      const int tau = mt * 8 + kp * 2;
      LOAD_A(afB, tau + 1)
      READ_B(bvB, kp * 2 + 1)
      MM(afA, bvA)
      LOAD_A(afA, tau + 2)
      READ_B(bvA, (kp * 2 + 2) & 7)
      MM(afB, bvB)
    }

    // per-mt epilogue: scores from LDS cn26 (broadcast), fold into running best
    {
      const int cnb = 131072 + (mt * 128 + g4 * 4) * 4;
      #pragma unroll
      for (int fn = 0; fn < 4; ++fn){
        #pragma unroll
        for (int fm = 0; fm < 8; ++fm){
          float4 cnr = *(const float4*)&lds[cnb + fm * 64];
          #pragma unroll
          for (int jj = 0; jj < 4; ++jj){
            int v = mt * 128 + fm * 16 + g4 * 4 + jj;
            float sc = ((const float*)&cnr)[jj] - 2.0f * acc[fm][fn][jj];
            u32 o = __float_as_uint(sc);
            o = (o & 0x80000000u) ? ~o : (o | 0x80000000u);
            best[fn] = umin64(best[fn], ((u64)o << 32) | (u32)v);
          }
        }
      }
      #pragma unroll
      for (int i = 0; i < 8; ++i)
        #pragma unroll
        for (int jj = 0; jj < 4; ++jj) acc[i][jj] = zero4;
    }
  }

  // per-wave reduce over the 4 lane-row-groups; direct store (no cross-wave)
  #pragma unroll
  for (int fn = 0; fn < 4; ++fn){
    best[fn] = umin64(best[fn], shfl_xor_u64(best[fn], 16));
    best[fn] = umin64(best[fn], shfl_xor_u64(best[fn], 32));
  }
  if (lane < 16){
    #pragma unroll
    for (int fn = 0; fn < 4; ++fn)
      okeys[bbase + wn * 64 + fn * 16 + lane] = best[fn];
  }

#undef LOAD_A
#undef READ_B
#undef MM
}

extern "C" void kernel_launch(void* const* d_in, const int* in_sizes, int n_in,
                              void* d_out, int out_size, void* d_ws, size_t ws_size,
                              hipStream_t stream){
  const float* x      = (const float*)d_in[0];
  const float* pre_w  = (const float*)d_in[1];
  const float* pre_b  = (const float*)d_in[2];
  const float* emb    = (const float*)d_in[3];
  const float* post_w = (const float*)d_in[4];
  const float* post_b = (const float*)d_in[5];

  float* z_out   = (float*)d_out;              // [256][512][256]
  float* zq_out  = z_out + 33554432;           // [256][512][256]
  float* rec_out = z_out + 67108864;           // [256][512][256]

  char* w = (char*)d_ws;
  u16* prew_b  = (u16*)(w);                    // 512KB
  u16* postw_b = (u16*)(w + 524288);           // 512KB
  u16* emb_b   = (u16*)(w + 1048576);          // 4MB (bf16, GEMM3)
  u8*  emb8    = (u8*)(w + 5242880);           // 2MB (fp8 permK)
  float* cn26  = (float*)(w + 7340032);        // 16KB
  u64* keys    = (u64*)(w + 7356416);          // 512KB
  u16* xb      = (u16*)(w + 7880704);          // 64MB [65536][512] bf16 (x^T)
  u8*  z8      = (u8*)(w + 74989568);          // 32MB [65536][512B] fp8 permK (z^T)

  k_cvt  <<<1024, 256, 0, stream>>>(pre_w, prew_b, 262144);
  k_cvt  <<<1024, 256, 0, stream>>>(post_w, postw_b, 262144);
  k_cvt  <<<8192, 256, 0, stream>>>(emb, emb_b, 2097152);
  k_cvt8 <<<2048, 256, 0, stream>>>(emb, emb8);
  k_cnorm<<<4096, 64, 0, stream>>>(emb, cn26);

  // x [b][c][s] -> xb [b][s][c]
  k_tcvt<<<8192, 256, 0, stream>>>(x, xb);

  // GEMM1: z = pre_w * x + pre_b ; fused z8 (fp8 permK transposed) write
  k_gemm<0><<<256 * 2 * 4, 256, 0, stream>>>(prew_b, xb,
      nullptr, pre_b, z_out, z8, 512, 2);

  // GEMM2: fp8 scores + fused argmin -> keys (A from L2, barrier-free loop)
  k_gemm2<<<256, 256, 0, stream>>>(emb8, z8, cn26, keys);

  // z_q gather (exact f32)
  k_zq<<<1024, 64, 0, stream>>>(keys, emb, zq_out);

  // GEMM3: rec = post_w * z_q + post_b (B = emb_b rows gathered via tokens)
  k_gemm<2><<<256 * 2 * 4, 256, 0, stream>>>(postw_b, emb_b,
      keys, post_b, rec_out, nullptr, 512, 2);
}

// Round 11
// 689.977 us; speedup vs baseline: 1.1759x; 1.1308x over previous
//
#include <hip/hip_runtime.h>
#include <hip/hip_bf16.h>

typedef unsigned short u16;
typedef unsigned char  u8;
typedef unsigned int   u32;
typedef unsigned long long u64;

using short8 = __attribute__((ext_vector_type(8))) short;
using f32x4  = __attribute__((ext_vector_type(4))) float;
using u16x8  = __attribute__((ext_vector_type(8))) unsigned short;
using ll2    = __attribute__((ext_vector_type(2))) long long;

#define AS_GLOBAL __attribute__((address_space(1)))
#define AS_LDS    __attribute__((address_space(3)))

// ---- bf16 helpers (manual RNE) ----
__device__ __forceinline__ u16 f2b(float x){
  u32 u = __float_as_uint(x);
  u32 r = (u + 0x7FFFu + ((u >> 16) & 1u)) >> 16;
  return (u16)r;
}
__device__ __forceinline__ float b2f(u16 h){ return __uint_as_float(((u32)h) << 16); }

// ---- fp8 OCP e4m3 (RNE, saturate 448) ----
__device__ __forceinline__ u32 f2e4m3(float x){
  float ax = fabsf(x);
  u32 s = (__float_as_uint(x) & 0x80000000u) >> 24;
  ax = fminf(ax, 448.0f);
  if (ax < 0.015625f){
    u32 m = (u32)__float2int_rn(ax * 512.0f);
    return s | m;
  }
  u32 u = __float_as_uint(ax);
  u32 man = u & 0x7FFFFFu;
  u32 rnd = man + 0x7FFFFu + ((man >> 20) & 1u);
  u32 e = (u >> 23) + (rnd >> 23);
  u32 m = (rnd >> 23) ? 0u : ((rnd >> 20) & 7u);
  if (e > 135u) return s | 0x7Eu;
  return s | ((e - 120u) << 3) | m;
}

__device__ __forceinline__ void gload16(u16* l, const u16* g){
  __builtin_amdgcn_global_load_lds((const AS_GLOBAL u32*)g, (AS_LDS u32*)l, 16, 0, 0);
}

__device__ __forceinline__ u64 umin64(u64 a, u64 b){ return a < b ? a : b; }

__device__ __forceinline__ u64 shfl_xor_u64(u64 v, int m){
  u32 lo = __shfl_xor((u32)v, m, 64);
  u32 hi = __shfl_xor((u32)(v >> 32), m, 64);
  return ((u64)hi << 32) | lo;
}

// ---- prep kernels ----
__global__ void k_cvt(const float* __restrict__ w, u16* __restrict__ d, int n){
  int i = blockIdx.x * 256 + threadIdx.x;
  if (i < n) d[i] = f2b(w[i]);
}

// emb f32 [4096][512] -> emb8 fp8 [4096][512B], K permuted: row byte
// pb = kb*64 + g*16 + ks*8 + j  <->  k = kb*64 + ks*32 + g*8 + j ; scale 2^20
__global__ void k_cvt8(const float* __restrict__ src, u8* __restrict__ dst){
  int id = blockIdx.x * 256 + threadIdx.x;
  int row = id >> 7, db = id & 127;
  int b0 = db * 4;
  int kb = b0 >> 6, r6 = b0 & 63;
  int g = r6 >> 4, ks = (r6 >> 3) & 1, j0 = r6 & 7;
  int k = kb * 64 + ks * 32 + g * 8 + j0;
  const float* p = src + (size_t)row * 512 + k;
  u32 w = f2e4m3(p[0] * 1048576.0f)
        | (f2e4m3(p[1] * 1048576.0f) << 8)
        | (f2e4m3(p[2] * 1048576.0f) << 16)
        | (f2e4m3(p[3] * 1048576.0f) << 24);
  *(u32*)(dst + (size_t)row * 512 + b0) = w;
}

// cnorm scaled by 2^26 (matches fp8 score scale 2^20 * 2^6)
__global__ void k_cnorm(const float* __restrict__ emb, float* __restrict__ cn26){
  int v = blockIdx.x, lane = threadIdx.x;
  const float* r = emb + (size_t)v * 512;
  float s = 0.f;
  #pragma unroll
  for (int i = 0; i < 8; ++i){ float x = r[lane + i * 64]; s += x * x; }
  #pragma unroll
  for (int off = 32; off; off >>= 1) s += __shfl_down(s, off, 64);
  if (lane == 0) cn26[v] = s * 67108864.0f;
}

// ---- transpose+convert: x f32 [256 b][512 r][256 c] -> xb bf16 [b][c][r] ----
__global__ void k_tcvt(const float* __restrict__ src, u16* __restrict__ d){
  __shared__ float t[64][65];
  const int bid = blockIdx.x;
  const int b  = bid >> 5;
  const int rb = (bid >> 2) & 7;
  const int cb = bid & 3;
  const float* s = src + ((size_t)b * 512 + (size_t)rb * 64) * 256 + cb * 64;
  const int tid = threadIdx.x;
  #pragma unroll
  for (int j = 0; j < 4; ++j){
    int fl = j * 256 + tid;
    int r = fl >> 4, c4 = (fl & 15) * 4;
    float4 v = *(const float4*)(s + (size_t)r * 256 + c4);
    t[r][c4 + 0] = v.x; t[r][c4 + 1] = v.y; t[r][c4 + 2] = v.z; t[r][c4 + 3] = v.w;
  }
  __syncthreads();
  u16* o = d + ((size_t)b * 256 + (size_t)cb * 64) * 512 + rb * 64;
  #pragma unroll
  for (int j = 0; j < 2; ++j){
    int fl = j * 256 + tid;
    int c = fl >> 3, r8 = (fl & 7) * 8;
    u16x8 hv;
    #pragma unroll
    for (int i = 0; i < 8; ++i) hv[i] = f2b(t[r8 + i][c]);
    *(u16x8*)(o + (size_t)c * 512 + r8) = hv;
  }
}

// ---- z_q gather ----
__global__ void k_zq(const u64* __restrict__ keys, const float* __restrict__ emb, float* __restrict__ zq){
  int sidx = blockIdx.x * 64 + threadIdx.x;
  int b = sidx >> 8, s = sidx & 255;
  int v = (int)(u32)keys[sidx];
  const float4* er = (const float4*)(emb + (size_t)v * 512);
  float* o = zq + (size_t)b * 512 * 256 + s;
  #pragma unroll 4
  for (int e4 = 0; e4 < 128; ++e4){
    float4 vv = er[e4];
    o[(size_t)(e4 * 4 + 0) * 256] = vv.x;
    o[(size_t)(e4 * 4 + 1) * 256] = vv.y;
    o[(size_t)(e4 * 4 + 2) * 256] = vv.z;
    o[(size_t)(e4 * 4 + 3) * 256] = vv.w;
  }
}

// ---- small GEMM (proven 128x128 2-phase): GEMM1 & GEMM3 ----
// MODE 0 additionally writes z8 = fp8(z*64) permK transposed from registers.
template<int MODE>
__global__ __launch_bounds__(256, 4) void k_gemm(
    const u16* __restrict__ Ah,
    const u16* __restrict__ Bh,
    const u64* __restrict__ gkeys,
    const float* __restrict__ bias,
    float* __restrict__ Cout,
    u8* __restrict__ Z8,
    int M, int mtbits)
{
  constexpr int K = 512;
  __shared__ __align__(16) u16 sA[128 * 64];
  __shared__ __align__(16) u16 sB[128 * 64];

  const int tid  = threadIdx.x;
  const int lane = tid & 63;
  const int wid  = tid >> 6;
  const int wm = wid >> 1, wn = wid & 1;

  const int nwg = gridDim.x;
  const int chunk = nwg >> 3;
  const int pb = blockIdx.x;
  const int bid = (pb & 7) * chunk + (pb >> 3);

  const int mt = bid & ((1 << mtbits) - 1);
  const int nt = (bid >> mtbits) & 1;
  const int b  = bid >> (mtbits + 1);
  const int m0 = mt * 128;
  const int n0 = nt * 128;
  const int bbase = b * 256;

  const u16* ga[4];
  const u16* gb[4];
  int ldso[4];
  #pragma unroll
  for (int i = 0; i < 4; ++i){
    int e = i * 256 + tid;
    int r = e >> 3;
    int sl = (e & 7) ^ (r & 7);
    ldso[i] = e * 8;
    ga[i] = Ah + (size_t)(m0 + r) * K + sl * 8;
    size_t brow;
    if (MODE == 2) brow = (size_t)(u32)gkeys[bbase + n0 + r];
    else           brow = (size_t)(bbase + n0 + r);
    gb[i] = Bh + brow * K + sl * 8;
  }

  const f32x4 zero4 = {0.f, 0.f, 0.f, 0.f};
  f32x4 acc[4][4];
  #pragma unroll
  for (int i = 0; i < 4; ++i)
    #pragma unroll
    for (int j = 0; j < 4; ++j) acc[i][j] = zero4;

  int aoff[2][4], boff[2][4];
  #pragma unroll
  for (int ks = 0; ks < 2; ++ks)
    #pragma unroll
    for (int f = 0; f < 4; ++f){
      int rA = wm * 64 + f * 16 + (lane & 15);
      aoff[ks][f] = rA * 64 + (((ks * 4 + (lane >> 4)) ^ (rA & 7)) * 8);
      int rB = wn * 64 + f * 16 + (lane & 15);
      boff[ks][f] = rB * 64 + (((ks * 4 + (lane >> 4)) ^ (rB & 7)) * 8);
    }

  for (int kt = 0; kt < 8; ++kt){
    const int k0 = kt * 64;
    #pragma unroll
    for (int i = 0; i < 4; ++i){
      gload16(&sA[ldso[i]], ga[i] + k0);
      gload16(&sB[ldso[i]], gb[i] + k0);
    }
    __syncthreads();
    #pragma unroll
    for (int ks = 0; ks < 2; ++ks){
      short8 ah[4], bh[4];
      #pragma unroll
      for (int f = 0; f < 4; ++f){
        ah[f] = *(const short8*)&sA[aoff[ks][f]];
        bh[f] = *(const short8*)&sB[boff[ks][f]];
      }
      #pragma unroll
      for (int fm = 0; fm < 4; ++fm)
        #pragma unroll
        for (int fn = 0; fn < 4; ++fn)
          acc[fm][fn] = __builtin_amdgcn_mfma_f32_16x16x32_bf16(ah[fm], bh[fn], acc[fm][fn], 0, 0, 0);
    }
    __syncthreads();
  }

  const int row0 = m0 + wm * 64;
  const int col  = n0 + wn * 64 + (lane & 15);
  float* Cb = Cout + (size_t)b * M * 256;
  #pragma unroll
  for (int fm = 0; fm < 4; ++fm){
    #pragma unroll
    for (int j = 0; j < 4; ++j){
      int row = row0 + fm * 16 + (lane >> 4) * 4 + j;
      float bi = bias[row];
      #pragma unroll
      for (int fn = 0; fn < 4; ++fn)
        Cb[(size_t)row * 256 + col + fn * 16] = acc[fm][fn][j] + bi;
    }
  }

  if (MODE == 0){
    // z8[(b*256+tok)][pb(k)] = fp8(z_k*64), pb = kb*64 + g*16 + ks*8 + j
    #pragma unroll
    for (int fm = 0; fm < 4; ++fm){
      int rb4 = row0 + fm * 16 + (lane >> 4) * 4;
      int pb0 = (rb4 >> 6) * 64 + (((rb4 >> 3) & 3) * 16) + (((rb4 >> 5) & 1) * 8) + (rb4 & 7);
      float bi0 = bias[rb4], bi1 = bias[rb4+1], bi2 = bias[rb4+2], bi3 = bias[rb4+3];
      #pragma unroll
      for (int fn = 0; fn < 4; ++fn){
        u32 w = f2e4m3((acc[fm][fn][0] + bi0) * 64.0f)
              | (f2e4m3((acc[fm][fn][1] + bi1) * 64.0f) << 8)
              | (f2e4m3((acc[fm][fn][2] + bi2) * 64.0f) << 16)
              | (f2e4m3((acc[fm][fn][3] + bi3) * 64.0f) << 24);
        *(u32*)(Z8 + (size_t)(bbase + col + fn * 16) * 512 + pb0) = w;
      }
    }
  }
}

// ---- GEMM2: fp8, B LDS-resident, pipelined A-fragment LDS reads ----
// One block/batch (256 blocks, 512 thr, 8 waves 2x4, 1/CU). LDS = 160KiB:
// B panel 128KB (slot^row&31, r9/r10-verified 0-conflict) + A dbuf 2x16KB.
// A tile = 256 rows x 64B fp8 (K=64), rotation swizzle slot=(g4+(row>>1))&3:
// service-group (16 lanes) hits 8 distinct 16B positions x 2 lanes = free
// (fixes r8's 8-way: row stride 64B spans only 2 positions unswizzled).
// PIPELINE (the round-4..8 fix): per K-tile ONE barrier; af(t+1) fragments
// ds_read into the *other* named register set BEFORE MFMA(t), so the LDS
// burst (~1150cy) is serviced DURING the MFMA window (~2500cy). Waits:
//   lgkm0 + vmcnt0 BEFORE the barrier (cross-wave: reads landed before the
//   staging overwrite; stages visible before reads). Compiler inserts the
//   fine-grained lgkmcnt(8) before MFMA's bv use (bv issued first).
// Registers: acc[8][4]=128 AGPR; afA/afB 64 + bv 16 + misc ~30 arch <=128
// (r7/r8-proven split at 8-wave blocks). Accum order == r8 -> same tokens.
__global__ __launch_bounds__(512, 1) void k_gemm2(
    const u8* __restrict__ A8,      // emb8 [4096][512B permK]
    const u8* __restrict__ B8,      // z8 [65536][512B permK]
    const float* __restrict__ cn26,
    u64* __restrict__ okeys)
{
  __shared__ __align__(16) u8 lds[163840];  // B 0..131071 | A dbuf 131072 + buf*16384

  const int tid  = threadIdx.x;
  const int lane = tid & 63;
  const int wid  = tid >> 6;
  const int wm   = wid >> 2;
  const int wn   = wid & 3;
  const int b    = blockIdx.x;
  const int bbase = b * 256;
  const int g4   = lane >> 4;

#define SB    __builtin_amdgcn_sched_barrier(0)
#define BAR   __builtin_amdgcn_s_barrier()
#define LGKM0 asm volatile("s_waitcnt lgkmcnt(0)" ::: "memory")
#define VM0   asm volatile("s_waitcnt vmcnt(0)" ::: "memory")
#define VM2   asm volatile("s_waitcnt vmcnt(2)" ::: "memory")

  // ---- B init: 128KB resident (pre-unswizzled source, linear dest) ----
  #pragma unroll
  for (int i = 0; i < 16; ++i){
    int e = i * 512 + tid;          // 16B-slot id 0..8191
    int t = e >> 5, s = e & 31;
    gload16((u16*)&lds[e * 16],
            (const u16*)(B8 + (size_t)(bbase + t) * 512 + ((s ^ (t & 31)) * 16)));
  }

  // ---- A staging descriptors: dest slot e linear, src slot g=(s-(row>>1))&3 ----
  const u8* gA0; const u8* gA1;
  {
    int r0 = tid >> 2, s0 = tid & 3;
    gA0 = A8 + (size_t)r0 * 512 + (((s0 - (r0 >> 1)) & 3) * 16);
    int e1 = tid + 512, r1 = e1 >> 2, s1 = e1 & 3;
    gA1 = A8 + (size_t)r1 * 512 + (((s1 - (r1 >> 1)) & 3) * 16);
  }

#define STG_A(tau_) { const u32 o_ = (u32)((((tau_) >> 3) & 15) * 131072) + (u32)(((tau_) & 7) * 64); \
    const int d_ = 131072 + (((tau_) & 1) * 16384); \
    gload16((u16*)&lds[d_ + tid * 16], (const u16*)(gA0 + o_)); \
    gload16((u16*)&lds[d_ + 8192 + tid * 16], (const u16*)(gA1 + o_)); }

  // A-frag read base: row = wm*128 + fm*16 + (lane&15); slot=(g4+((lane&15)>>1))&3
  // (fm*16, wm*128 are 0 mod 8 -> slot lane-const across fm)
  const int aOff = 131072 + wm * 8192 + (lane & 15) * 64
                 + (((g4 + ((lane & 15) >> 1)) & 3) * 16);
  // B-frag bases; addr(kt) = bB0 ^ (kt<<6) (kt*4 and g4 occupy disjoint slot bits)
  int bB0[4];
  #pragma unroll
  for (int fn = 0; fn < 4; ++fn){
    int t_ = wn * 64 + fn * 16 + (lane & 15);
    bB0[fn] = t_ * 512 + ((g4 ^ (t_ & 31)) * 16);
  }

#define READ_AF(dst, bsel) { _Pragma("unroll") for (int fm = 0; fm < 8; ++fm) \
    dst[fm] = *(const ll2*)&lds[aOff + (bsel) * 16384 + fm * 1024]; }
#define READ_BV(ktc) { _Pragma("unroll") for (int fn = 0; fn < 4; ++fn) \
    bv[fn] = *(const ll2*)&lds[bB0[fn] ^ ((ktc) << 6)]; }
#define MM(af) { __builtin_amdgcn_s_setprio(1); \
  _Pragma("unroll") for (int fm = 0; fm < 8; ++fm) \
    _Pragma("unroll") for (int fn = 0; fn < 4; ++fn){ \
      acc[fm][fn] = __builtin_amdgcn_mfma_f32_16x16x32_fp8_fp8(af[fm][0], bv[fn][0], acc[fm][fn], 0, 0, 0); \
      acc[fm][fn] = __builtin_amdgcn_mfma_f32_16x16x32_fp8_fp8(af[fm][1], bv[fn][1], acc[fm][fn], 0, 0, 0); } \
  __builtin_amdgcn_s_setprio(0); }

  const f32x4 zero4 = {0.f, 0.f, 0.f, 0.f};
  f32x4 acc[8][4];
  #pragma unroll
  for (int i = 0; i < 8; ++i)
    #pragma unroll
    for (int j = 0; j < 4; ++j) acc[i][j] = zero4;

  u64 best[4];
  #pragma unroll
  for (int i = 0; i < 4; ++i) best[i] = ~0ull;

  ll2 afA[8], afB[8], bv[4];

  // prologue: stage tiles 0,1; wait B-init + tile0; preload af(0)
  STG_A(0)
  STG_A(1)
  VM2; BAR; SB;
  READ_AF(afA, 0)

  #pragma unroll 1
  for (int mt = 0; mt < 16; ++mt){
    #pragma unroll
    for (int kt = 0; kt < 8; ++kt){
      const int tau = mt * 8 + kt;
      // lgkm0: my frag reads landed (before others overwrite their source)
      // vmcnt0: my stages done (before others read them); then align
      LGKM0; VM0; SB; BAR; SB;
      READ_BV(kt)                                 // for MFMA(t) (issued first)
      if (kt & 1){ READ_AF(afA, ((kt + 1) & 1)) } // frags for tile t+1
      else       { READ_AF(afB, ((kt + 1) & 1)) }
      STG_A(tau + 2)                              // into buf[t&1] (tile t read last iter)
      SB;
      if (kt & 1){ MM(afB) } else { MM(afA) }     // LDS services reads during MFMA
    }

    // per-mt epilogue: scores = cn26 - 2*acc (cn from global, L2-hot), fold argmin
    {
      const float4* cp = (const float4*)(cn26 + mt * 256 + wm * 128 + g4 * 4);
      float4 cnr[8];
      #pragma unroll
      for (int fm = 0; fm < 8; ++fm) cnr[fm] = cp[fm * 4];
      #pragma unroll
      for (int fn = 0; fn < 4; ++fn){
        #pragma unroll
        for (int fm = 0; fm < 8; ++fm){
          #pragma unroll
          for (int jj = 0; jj < 4; ++jj){
            int v = mt * 256 + wm * 128 + fm * 16 + g4 * 4 + jj;
            float sc = ((const float*)&cnr[fm])[jj] - 2.0f * acc[fm][fn][jj];
            u32 o = __float_as_uint(sc);
            o = (o & 0x80000000u) ? ~o : (o | 0x80000000u);
            best[fn] = umin64(best[fn], ((u64)o << 32) | (u32)v);
          }
        }
      }
      #pragma unroll
      for (int i = 0; i < 8; ++i)
        #pragma unroll
        for (int jj = 0; jj < 4; ++jj) acc[i][jj] = zero4;
    }
  }

  // block reduce + single store
  #pragma unroll
  for (int fn = 0; fn < 4; ++fn){
    best[fn] = umin64(best[fn], shfl_xor_u64(best[fn], 16));
    best[fn] = umin64(best[fn], shfl_xor_u64(best[fn], 32));
  }
  __syncthreads();
  u64* kbuf = (u64*)&lds[131072];
  if (lane < 16){
    #pragma unroll
    for (int fn = 0; fn < 4; ++fn)
      kbuf[wm * 256 + wn * 64 + fn * 16 + lane] = best[fn];
  }
  __syncthreads();
  if (tid < 256)
    okeys[bbase + tid] = umin64(kbuf[tid], kbuf[256 + tid]);

#undef STG_A
#undef READ_AF
#undef READ_BV
#undef MM
#undef SB
#undef BAR
#undef LGKM0
#undef VM0
#undef VM2
}

extern "C" void kernel_launch(void* const* d_in, const int* in_sizes, int n_in,
                              void* d_out, int out_size, void* d_ws, size_t ws_size,
                              hipStream_t stream){
  const float* x      = (const float*)d_in[0];
  const float* pre_w  = (const float*)d_in[1];
  const float* pre_b  = (const float*)d_in[2];
  const float* emb    = (const float*)d_in[3];
  const float* post_w = (const float*)d_in[4];
  const float* post_b = (const float*)d_in[5];

  float* z_out   = (float*)d_out;              // [256][512][256]
  float* zq_out  = z_out + 33554432;           // [256][512][256]
  float* rec_out = z_out + 67108864;           // [256][512][256]

  char* w = (char*)d_ws;
  u16* prew_b  = (u16*)(w);                    // 512KB
  u16* postw_b = (u16*)(w + 524288);           // 512KB
  u16* emb_b   = (u16*)(w + 1048576);          // 4MB (bf16, GEMM3)
  u8*  emb8    = (u8*)(w + 5242880);           // 2MB (fp8 permK)
  float* cn26  = (float*)(w + 7340032);        // 16KB
  u64* keys    = (u64*)(w + 7356416);          // 512KB
  u16* xb      = (u16*)(w + 7880704);          // 64MB [65536][512] bf16 (x^T)
  u8*  z8      = (u8*)(w + 74989568);          // 32MB [65536][512B] fp8 permK (z^T)

  k_cvt  <<<1024, 256, 0, stream>>>(pre_w, prew_b, 262144);
  k_cvt  <<<1024, 256, 0, stream>>>(post_w, postw_b, 262144);
  k_cvt  <<<8192, 256, 0, stream>>>(emb, emb_b, 2097152);
  k_cvt8 <<<2048, 256, 0, stream>>>(emb, emb8);
  k_cnorm<<<4096, 64, 0, stream>>>(emb, cn26);

  // x [b][c][s] -> xb [b][s][c]
  k_tcvt<<<8192, 256, 0, stream>>>(x, xb);

  // GEMM1: z = pre_w * x + pre_b ; fused z8 (fp8 permK transposed) write
  k_gemm<0><<<256 * 2 * 4, 256, 0, stream>>>(prew_b, xb,
      nullptr, pre_b, z_out, z8, 512, 2);

  // GEMM2: fp8 scores + fused argmin -> keys (pipelined LDS reads)
  k_gemm2<<<256, 512, 0, stream>>>(emb8, z8, cn26, keys);

  // z_q gather (exact f32)
  k_zq<<<1024, 64, 0, stream>>>(keys, emb, zq_out);

  // GEMM3: rec = post_w * z_q + post_b (B = emb_b rows gathered via tokens)
  k_gemm<2><<<256 * 2 * 4, 256, 0, stream>>>(postw_b, emb_b,
      keys, post_b, rec_out, nullptr, 512, 2);
}

// Round 12
// 561.051 us; speedup vs baseline: 1.4461x; 1.2298x over previous
//
#include <hip/hip_runtime.h>
#include <hip/hip_bf16.h>

typedef unsigned short u16;
typedef unsigned char  u8;
typedef unsigned int   u32;
typedef unsigned long long u64;

using short8 = __attribute__((ext_vector_type(8))) short;
using f32x4  = __attribute__((ext_vector_type(4))) float;
using u16x8  = __attribute__((ext_vector_type(8))) unsigned short;
using ll2    = __attribute__((ext_vector_type(2))) long long;

#define AS_GLOBAL __attribute__((address_space(1)))
#define AS_LDS    __attribute__((address_space(3)))

// ---- bf16 helpers (manual RNE) ----
__device__ __forceinline__ u16 f2b(float x){
  u32 u = __float_as_uint(x);
  u32 r = (u + 0x7FFFu + ((u >> 16) & 1u)) >> 16;
  return (u16)r;
}
__device__ __forceinline__ float b2f(u16 h){ return __uint_as_float(((u32)h) << 16); }

// ---- fp8 OCP e4m3 (RNE, saturate 448) ----
__device__ __forceinline__ u32 f2e4m3(float x){
  float ax = fabsf(x);
  u32 s = (__float_as_uint(x) & 0x80000000u) >> 24;
  ax = fminf(ax, 448.0f);
  if (ax < 0.015625f){
    u32 m = (u32)__float2int_rn(ax * 512.0f);
    return s | m;
  }
  u32 u = __float_as_uint(ax);
  u32 man = u & 0x7FFFFFu;
  u32 rnd = man + 0x7FFFFu + ((man >> 20) & 1u);
  u32 e = (u >> 23) + (rnd >> 23);
  u32 m = (rnd >> 23) ? 0u : ((rnd >> 20) & 7u);
  if (e > 135u) return s | 0x7Eu;
  return s | ((e - 120u) << 3) | m;
}

__device__ __forceinline__ void gload16(u16* l, const u16* g){
  __builtin_amdgcn_global_load_lds((const AS_GLOBAL u32*)g, (AS_LDS u32*)l, 16, 0, 0);
}

__device__ __forceinline__ u64 umin64(u64 a, u64 b){ return a < b ? a : b; }

__device__ __forceinline__ u64 shfl_xor_u64(u64 v, int m){
  u32 lo = __shfl_xor((u32)v, m, 64);
  u32 hi = __shfl_xor((u32)(v >> 32), m, 64);
  return ((u64)hi << 32) | lo;
}

// ---- prep kernels ----
__global__ void k_cvt(const float* __restrict__ w, u16* __restrict__ d, int n){
  int i = blockIdx.x * 256 + threadIdx.x;
  if (i < n) d[i] = f2b(w[i]);
}

// emb f32 [4096][512] -> emb8 fp8 [4096][512B], K permuted: row byte
// pb = kb*64 + g*16 + ks*8 + j  <->  k = kb*64 + ks*32 + g*8 + j ; scale 2^20
__global__ void k_cvt8(const float* __restrict__ src, u8* __restrict__ dst){
  int id = blockIdx.x * 256 + threadIdx.x;
  int row = id >> 7, db = id & 127;
  int b0 = db * 4;
  int kb = b0 >> 6, r6 = b0 & 63;
  int g = r6 >> 4, ks = (r6 >> 3) & 1, j0 = r6 & 7;
  int k = kb * 64 + ks * 32 + g * 8 + j0;
  const float* p = src + (size_t)row * 512 + k;
  u32 w = f2e4m3(p[0] * 1048576.0f)
        | (f2e4m3(p[1] * 1048576.0f) << 8)
        | (f2e4m3(p[2] * 1048576.0f) << 16)
        | (f2e4m3(p[3] * 1048576.0f) << 24);
  *(u32*)(dst + (size_t)row * 512 + b0) = w;
}

// cnorm scaled by 2^26 (matches fp8 score scale 2^20 * 2^6)
__global__ void k_cnorm(const float* __restrict__ emb, float* __restrict__ cn26){
  int v = blockIdx.x, lane = threadIdx.x;
  const float* r = emb + (size_t)v * 512;
  float s = 0.f;
  #pragma unroll
  for (int i = 0; i < 8; ++i){ float x = r[lane + i * 64]; s += x * x; }
  #pragma unroll
  for (int off = 32; off; off >>= 1) s += __shfl_down(s, off, 64);
  if (lane == 0) cn26[v] = s * 67108864.0f;
}

// ---- transpose+convert: x f32 [256 b][512 r][256 c] -> xb bf16 [b][c][r] ----
__global__ void k_tcvt(const float* __restrict__ src, u16* __restrict__ d){
  __shared__ float t[64][65];
  const int bid = blockIdx.x;
  const int b  = bid >> 5;
  const int rb = (bid >> 2) & 7;
  const int cb = bid & 3;
  const float* s = src + ((size_t)b * 512 + (size_t)rb * 64) * 256 + cb * 64;
  const int tid = threadIdx.x;
  #pragma unroll
  for (int j = 0; j < 4; ++j){
    int fl = j * 256 + tid;
    int r = fl >> 4, c4 = (fl & 15) * 4;
    float4 v = *(const float4*)(s + (size_t)r * 256 + c4);
    t[r][c4 + 0] = v.x; t[r][c4 + 1] = v.y; t[r][c4 + 2] = v.z; t[r][c4 + 3] = v.w;
  }
  __syncthreads();
  u16* o = d + ((size_t)b * 256 + (size_t)cb * 64) * 512 + rb * 64;
  #pragma unroll
  for (int j = 0; j < 2; ++j){
    int fl = j * 256 + tid;
    int c = fl >> 3, r8 = (fl & 7) * 8;
    u16x8 hv;
    #pragma unroll
    for (int i = 0; i < 8; ++i) hv[i] = f2b(t[r8 + i][c]);
    *(u16x8*)(o + (size_t)c * 512 + r8) = hv;
  }
}

// ---- z_q gather ----
__global__ void k_zq(const u64* __restrict__ keys, const float* __restrict__ emb, float* __restrict__ zq){
  int sidx = blockIdx.x * 64 + threadIdx.x;
  int b = sidx >> 8, s = sidx & 255;
  int v = (int)(u32)keys[sidx];
  const float4* er = (const float4*)(emb + (size_t)v * 512);
  float* o = zq + (size_t)b * 512 * 256 + s;
  #pragma unroll 4
  for (int e4 = 0; e4 < 128; ++e4){
    float4 vv = er[e4];
    o[(size_t)(e4 * 4 + 0) * 256] = vv.x;
    o[(size_t)(e4 * 4 + 1) * 256] = vv.y;
    o[(size_t)(e4 * 4 + 2) * 256] = vv.z;
    o[(size_t)(e4 * 4 + 3) * 256] = vv.w;
  }
}

// ---- small GEMM (proven 128x128 2-phase): GEMM1 & GEMM3 ----
// MODE 0 additionally writes z8 = fp8(z*64) permK transposed from registers.
template<int MODE>
__global__ __launch_bounds__(256, 4) void k_gemm(
    const u16* __restrict__ Ah,
    const u16* __restrict__ Bh,
    const u64* __restrict__ gkeys,
    const float* __restrict__ bias,
    float* __restrict__ Cout,
    u8* __restrict__ Z8,
    int M, int mtbits)
{
  constexpr int K = 512;
  __shared__ __align__(16) u16 sA[128 * 64];
  __shared__ __align__(16) u16 sB[128 * 64];

  const int tid  = threadIdx.x;
  const int lane = tid & 63;
  const int wid  = tid >> 6;
  const int wm = wid >> 1, wn = wid & 1;

  const int nwg = gridDim.x;
  const int chunk = nwg >> 3;
  const int pb = blockIdx.x;
  const int bid = (pb & 7) * chunk + (pb >> 3);

  const int mt = bid & ((1 << mtbits) - 1);
  const int nt = (bid >> mtbits) & 1;
  const int b  = bid >> (mtbits + 1);
  const int m0 = mt * 128;
  const int n0 = nt * 128;
  const int bbase = b * 256;

  const u16* ga[4];
  const u16* gb[4];
  int ldso[4];
  #pragma unroll
  for (int i = 0; i < 4; ++i){
    int e = i * 256 + tid;
    int r = e >> 3;
    int sl = (e & 7) ^ (r & 7);
    ldso[i] = e * 8;
    ga[i] = Ah + (size_t)(m0 + r) * K + sl * 8;
    size_t brow;
    if (MODE == 2) brow = (size_t)(u32)gkeys[bbase + n0 + r];
    else           brow = (size_t)(bbase + n0 + r);
    gb[i] = Bh + brow * K + sl * 8;
  }

  const f32x4 zero4 = {0.f, 0.f, 0.f, 0.f};
  f32x4 acc[4][4];
  #pragma unroll
  for (int i = 0; i < 4; ++i)
    #pragma unroll
    for (int j = 0; j < 4; ++j) acc[i][j] = zero4;

  int aoff[2][4], boff[2][4];
  #pragma unroll
  for (int ks = 0; ks < 2; ++ks)
    #pragma unroll
    for (int f = 0; f < 4; ++f){
      int rA = wm * 64 + f * 16 + (lane & 15);
      aoff[ks][f] = rA * 64 + (((ks * 4 + (lane >> 4)) ^ (rA & 7)) * 8);
      int rB = wn * 64 + f * 16 + (lane & 15);
      boff[ks][f] = rB * 64 + (((ks * 4 + (lane >> 4)) ^ (rB & 7)) * 8);
    }

  for (int kt = 0; kt < 8; ++kt){
    const int k0 = kt * 64;
    #pragma unroll
    for (int i = 0; i < 4; ++i){
      gload16(&sA[ldso[i]], ga[i] + k0);
      gload16(&sB[ldso[i]], gb[i] + k0);
    }
    __syncthreads();
    #pragma unroll
    for (int ks = 0; ks < 2; ++ks){
      short8 ah[4], bh[4];
      #pragma unroll
      for (int f = 0; f < 4; ++f){
        ah[f] = *(const short8*)&sA[aoff[ks][f]];
        bh[f] = *(const short8*)&sB[boff[ks][f]];
      }
      #pragma unroll
      for (int fm = 0; fm < 4; ++fm)
        #pragma unroll
        for (int fn = 0; fn < 4; ++fn)
          acc[fm][fn] = __builtin_amdgcn_mfma_f32_16x16x32_bf16(ah[fm], bh[fn], acc[fm][fn], 0, 0, 0);
    }
    __syncthreads();
  }

  const int row0 = m0 + wm * 64;
  const int col  = n0 + wn * 64 + (lane & 15);
  float* Cb = Cout + (size_t)b * M * 256;
  #pragma unroll
  for (int fm = 0; fm < 4; ++fm){
    #pragma unroll
    for (int j = 0; j < 4; ++j){
      int row = row0 + fm * 16 + (lane >> 4) * 4 + j;
      float bi = bias[row];
      #pragma unroll
      for (int fn = 0; fn < 4; ++fn)
        Cb[(size_t)row * 256 + col + fn * 16] = acc[fm][fn][j] + bi;
    }
  }

  if (MODE == 0){
    // z8[(b*256+tok)][pb(k)] = fp8(z_k*64), pb = kb*64 + g*16 + ks*8 + j
    #pragma unroll
    for (int fm = 0; fm < 4; ++fm){
      int rb4 = row0 + fm * 16 + (lane >> 4) * 4;
      int pb0 = (rb4 >> 6) * 64 + (((rb4 >> 3) & 3) * 16) + (((rb4 >> 5) & 1) * 8) + (rb4 & 7);
      float bi0 = bias[rb4], bi1 = bias[rb4+1], bi2 = bias[rb4+2], bi3 = bias[rb4+3];
      #pragma unroll
      for (int fn = 0; fn < 4; ++fn){
        u32 w = f2e4m3((acc[fm][fn][0] + bi0) * 64.0f)
              | (f2e4m3((acc[fm][fn][1] + bi1) * 64.0f) << 8)
              | (f2e4m3((acc[fm][fn][2] + bi2) * 64.0f) << 16)
              | (f2e4m3((acc[fm][fn][3] + bi3) * 64.0f) << 24);
        *(u32*)(Z8 + (size_t)(bbase + col + fn * 16) * 512 + pb0) = w;
      }
    }
  }
}

// ---- GEMM2: r8 structure + rotation-swizzled A tile (ONLY delta vs r8) ----
// One block per batch (256 blocks, 512 thr, 8 waves 2x4, 1/CU, LDS=160KiB).
// B = z8 panel 128KB LDS-resident, slot-XOR s^(t&31) (0-conflict, verified).
// A = emb8 streamed (dbuf 2x16KB). ROTATION SWIZZLE (r11-verified 0-conflict):
//   LDS[row][s] = G[row][(s-(row>>1))&3]  (4x16B slots per 64B row)
//   read slot for G-slot g4: (g4+(row>>1))&3; 16-lane service group ->
//   8 distinct 16B positions x 2 lanes = 2-way = free (m136). Fixes r8's
//   8-way conflict (8.4M cycles: row stride 64B -> 2 positions unswizzled).
// Register pressure identical to r8 (proven spill-free: WRITE 17KB).
// Accumulation order identical to r8 -> bit-identical tokens.
__global__ __launch_bounds__(512, 1) void k_gemm2(
    const u8* __restrict__ A8,      // emb8 [4096][512B permK]
    const u8* __restrict__ B8,      // z8 [65536][512B permK]
    const float* __restrict__ cn26,
    u64* __restrict__ okeys)
{
  __shared__ __align__(16) u8 lds[163840];  // B 0..131071 | A dbuf 131072 + buf*16384

  const int tid  = threadIdx.x;
  const int lane = tid & 63;
  const int wid  = tid >> 6;
  const int wm   = wid >> 2;
  const int wn   = wid & 3;
  const int b    = blockIdx.x;
  const int bbase = b * 256;
  const int g4   = lane >> 4;

#define SB    __builtin_amdgcn_sched_barrier(0)
#define BAR   __builtin_amdgcn_s_barrier()
#define LGKM0 asm volatile("s_waitcnt lgkmcnt(0)" ::: "memory")
#define VM2   asm volatile("s_waitcnt vmcnt(2)" ::: "memory")
#define VM0   asm volatile("s_waitcnt vmcnt(0)" ::: "memory")

  // ---- B init: 128KB resident ----
  #pragma unroll
  for (int i = 0; i < 16; ++i){
    int e = i * 512 + tid;          // 16B-slot id 0..8191
    int t = e >> 5, s = e & 31;
    gload16((u16*)&lds[e * 16],
            (const u16*)(B8 + (size_t)(bbase + t) * 512 + ((s ^ (t & 31)) * 16)));
  }

  // ---- A staging: dest linear (e=tid -> row=tid>>2, slot=tid&3);
  //      source slot rotation-unswizzled: (s - (row>>1)) & 3 ----
  const u8* gsrcA0;
  const u8* gsrcA1;
  {
    int r0 = tid >> 2, s0 = tid & 3;
    int sl0 = (s0 - (r0 >> 1)) & 3;
    gsrcA0 = A8 + (size_t)r0 * 512 + sl0 * 16;
    int r1 = r0 + 128;
    int sl1 = (s0 - (r1 >> 1)) & 3;
    gsrcA1 = A8 + (size_t)r1 * 512 + sl1 * 16;
  }

#define STG_A(tp) { const size_t _o = (size_t)((tp) >> 3) * 131072 + ((tp) & 7) * 64; \
    const int _d = 131072 + (((tp) & 1) * 16384); \
    gload16((u16*)&lds[_d + tid * 16], (const u16*)(gsrcA0 + _o)); \
    gload16((u16*)&lds[_d + 8192 + tid * 16], (const u16*)(gsrcA1 + _o)); }

  // ds_read bases: row = wm*128 + fm*16 + (lane&15); rotation slot is
  // lane-constant across fm ((wm*128+fm*16)>>1 ≡ 0 mod 4)
  int aBase[8];
  #pragma unroll
  for (int fm = 0; fm < 8; ++fm){
    int row = wm * 128 + fm * 16 + (lane & 15);
    int sl = (g4 + ((lane & 15) >> 1)) & 3;
    aBase[fm] = 131072 + row * 64 + sl * 16;
  }
  int tB[4], mB[4];
  #pragma unroll
  for (int fn = 0; fn < 4; ++fn){
    tB[fn] = wn * 64 + fn * 16 + (lane & 15);
    mB[fn] = tB[fn] & 31;
  }

  const f32x4 zero4 = {0.f, 0.f, 0.f, 0.f};
  f32x4 acc[8][4];
  #pragma unroll
  for (int i = 0; i < 8; ++i)
    #pragma unroll
    for (int j = 0; j < 4; ++j) acc[i][j] = zero4;

  u64 best[4];
  #pragma unroll
  for (int i = 0; i < 4; ++i) best[i] = ~0ull;

  STG_A(0)

  for (int mt = 0; mt < 16; ++mt){
    #pragma unroll
    for (int kt = 0; kt < 8; ++kt){
      const int tau = mt * 8 + kt;
      if (tau < 127) STG_A(tau + 1)
      if (tau == 127){ VM0; } else { VM2; }
      SB; BAR; SB;

      const int bufo = (tau & 1) * 16384;
      ll2 af[8], bv[4];
      #pragma unroll
      for (int fm = 0; fm < 8; ++fm)
        af[fm] = *(const ll2*)&lds[aBase[fm] + bufo];
      #pragma unroll
      for (int fn = 0; fn < 4; ++fn)
        bv[fn] = *(const ll2*)&lds[tB[fn] * 512 + (((kt * 4 + g4) ^ mB[fn]) * 16)];
      LGKM0; SB; BAR; SB;

      __builtin_amdgcn_s_setprio(1);
      #pragma unroll
      for (int fm = 0; fm < 8; ++fm)
        #pragma unroll
        for (int fn = 0; fn < 4; ++fn){
          acc[fm][fn] = __builtin_amdgcn_mfma_f32_16x16x32_fp8_fp8(af[fm][0], bv[fn][0], acc[fm][fn], 0, 0, 0);
          acc[fm][fn] = __builtin_amdgcn_mfma_f32_16x16x32_fp8_fp8(af[fm][1], bv[fn][1], acc[fm][fn], 0, 0, 0);
        }
      __builtin_amdgcn_s_setprio(0);
      SB;
    }

    // per-mt epilogue: cn26 fragment from global (L2-hot, broadcast), fold argmin
    {
      const float4* cp = (const float4*)(cn26 + mt * 256 + wm * 128 + g4 * 4);
      float4 cnr[8];
      #pragma unroll
      for (int fm = 0; fm < 8; ++fm) cnr[fm] = cp[fm * 4];
      VM0;   // drains cn loads (and next-tile staging early; harmless)
      #pragma unroll
      for (int fn = 0; fn < 4; ++fn){
        #pragma unroll
        for (int fm = 0; fm < 8; ++fm){
          #pragma unroll
          for (int jj = 0; jj < 4; ++jj){
            int v = mt * 256 + wm * 128 + fm * 16 + g4 * 4 + jj;
            float sc = ((const float*)&cnr[fm])[jj] - 2.0f * acc[fm][fn][jj];
            u32 o = __float_as_uint(sc);
            o = (o & 0x80000000u) ? ~o : (o | 0x80000000u);
            best[fn] = umin64(best[fn], ((u64)o << 32) | (u32)v);
          }
        }
      }
      #pragma unroll
      for (int i = 0; i < 8; ++i)
        #pragma unroll
        for (int jj = 0; jj < 4; ++jj) acc[i][jj] = zero4;
    }
  }

  // block reduce + single store
  #pragma unroll
  for (int fn = 0; fn < 4; ++fn){
    best[fn] = umin64(best[fn], shfl_xor_u64(best[fn], 16));
    best[fn] = umin64(best[fn], shfl_xor_u64(best[fn], 32));
  }
  __syncthreads();
  u64* kbuf = (u64*)&lds[131072];
  if (lane < 16){
    #pragma unroll
    for (int fn = 0; fn < 4; ++fn)
      kbuf[wm * 256 + wn * 64 + fn * 16 + lane] = best[fn];
  }
  __syncthreads();
  if (tid < 256)
    okeys[bbase + tid] = umin64(kbuf[tid], kbuf[256 + tid]);

#undef STG_A
#undef SB
#undef BAR
#undef LGKM0
#undef VM2
#undef VM0
}

extern "C" void kernel_launch(void* const* d_in, const int* in_sizes, int n_in,
                              void* d_out, int out_size, void* d_ws, size_t ws_size,
                              hipStream_t stream){
  const float* x      = (const float*)d_in[0];
  const float* pre_w  = (const float*)d_in[1];
  const float* pre_b  = (const float*)d_in[2];
  const float* emb    = (const float*)d_in[3];
  const float* post_w = (const float*)d_in[4];
  const float* post_b = (const float*)d_in[5];

  float* z_out   = (float*)d_out;              // [256][512][256]
  float* zq_out  = z_out + 33554432;           // [256][512][256]
  float* rec_out = z_out + 67108864;           // [256][512][256]

  char* w = (char*)d_ws;
  u16* prew_b  = (u16*)(w);                    // 512KB
  u16* postw_b = (u16*)(w + 524288);           // 512KB
  u16* emb_b   = (u16*)(w + 1048576);          // 4MB (bf16, GEMM3)
  u8*  emb8    = (u8*)(w + 5242880);           // 2MB (fp8 permK)
  float* cn26  = (float*)(w + 7340032);        // 16KB
  u64* keys    = (u64*)(w + 7356416);          // 512KB
  u16* xb      = (u16*)(w + 7880704);          // 64MB [65536][512] bf16 (x^T)
  u8*  z8      = (u8*)(w + 74989568);          // 32MB [65536][512B] fp8 permK (z^T)

  k_cvt  <<<1024, 256, 0, stream>>>(pre_w, prew_b, 262144);
  k_cvt  <<<1024, 256, 0, stream>>>(post_w, postw_b, 262144);
  k_cvt  <<<8192, 256, 0, stream>>>(emb, emb_b, 2097152);
  k_cvt8 <<<2048, 256, 0, stream>>>(emb, emb8);
  k_cnorm<<<4096, 64, 0, stream>>>(emb, cn26);

  // x [b][c][s] -> xb [b][s][c]
  k_tcvt<<<8192, 256, 0, stream>>>(x, xb);

  // GEMM1: z = pre_w * x + pre_b ; fused z8 (fp8 permK transposed) write
  k_gemm<0><<<256 * 2 * 4, 256, 0, stream>>>(prew_b, xb,
      nullptr, pre_b, z_out, z8, 512, 2);

  // GEMM2: fp8 scores + fused argmin -> keys (conflict-free A reads)
  k_gemm2<<<256, 512, 0, stream>>>(emb8, z8, cn26, keys);

  // z_q gather (exact f32)
  k_zq<<<1024, 64, 0, stream>>>(keys, emb, zq_out);

  // GEMM3: rec = post_w * z_q + post_b (B = emb_b rows gathered via tokens)
  k_gemm<2><<<256 * 2 * 4, 256, 0, stream>>>(postw_b, emb_b,
      keys, post_b, rec_out, nullptr, 512, 2);
}